// Round 1
// baseline (365.192 us; speedup 1.0000x reference)
//
#include <hip/hip_runtime.h>

// WeightedDiceLoss on MI355X.
// input, target: (64,1,512,512) fp32. Output: scalar fp32.
// weight = 1 + 5*|box31(target) - target|, box31 = separable 31x31 box filter,
// zero padding 15, always divide by 961 (count_include_pad=True).
// loss = 1 - (2*sum(i*t*w) + 1) / (sum(i*w) + sum(t*w) + 1)

#define BATCH 64
#define H     512
#define W     512
#define KW    31
#define PADR  15
#define NSEG  4            // vertical segments per column (occupancy)
#define SEG   (H / NSEG)   // 128

// ---------------------------------------------------------------------------
// Pass 1: vertical box sum over target -> colsum[b,h,w] = sum_{j=h-15..h+15} t
// One thread per (b, seg, w); running sliding-window sum down the column.
// Coalesced across w (consecutive threads -> consecutive w).
// ---------------------------------------------------------------------------
__global__ __launch_bounds__(256) void vbox_kernel(const float* __restrict__ tgt,
                                                   float* __restrict__ colsum) {
    const int t    = blockIdx.x * 256 + threadIdx.x;   // 0 .. BATCH*NSEG*W-1
    const int w    = t & (W - 1);
    const int rest = t >> 9;                           // / W
    const int seg  = rest & (NSEG - 1);
    const int b    = rest >> 2;                        // / NSEG
    const size_t base = (size_t)b * H * W + w;
    const int h0 = seg * SEG;

    // initial window for h = h0 covers rows [h0-15, h0+15] clipped to [0,H)
    float run = 0.f;
    #pragma unroll
    for (int j = -PADR; j <= PADR; ++j) {
        int r = h0 + j;
        if (r >= 0 && r < H) run += tgt[base + (size_t)r * W];
    }

    #pragma unroll 4
    for (int h = h0; h < h0 + SEG; ++h) {
        colsum[base + (size_t)h * W] = run;
        const int add = h + PADR + 1;
        const int sub = h - PADR;
        if (add < H)  run += tgt[base + (size_t)add * W];
        if (sub >= 0) run -= tgt[base + (size_t)sub * W];
    }
}

// ---------------------------------------------------------------------------
// Pass 2: horizontal box sum (register sliding window) + fused weighted sums.
// One wave (64 lanes) per image row; lane handles 8 consecutive columns.
// Lane loads colsum cols [col0-16, col0+24) as 10 float4 (L1 absorbs the
// 2x overlap between neighboring lanes); no LDS -> no bank conflicts.
// ---------------------------------------------------------------------------
__global__ __launch_bounds__(256) void hbox_reduce_kernel(const float* __restrict__ colsum,
                                                          const float* __restrict__ tgt,
                                                          const float* __restrict__ inp,
                                                          float* __restrict__ acc) {
    const int wave = threadIdx.x >> 6;
    const int lane = threadIdx.x & 63;
    const int row  = blockIdx.x * 4 + wave;            // 0 .. BATCH*H-1
    const size_t rowbase = (size_t)row * W;
    const int col0 = lane * 8;

    // r[k] holds colsum at column (col0 - 16 + k), k = 0..39.
    // Reads may cross row boundaries / array edges by <=64B (workspace has
    // slack on both sides); invalid entries are zeroed below (zero padding).
    float r[40];
    const float* p = colsum + rowbase + col0 - 16;
    #pragma unroll
    for (int k = 0; k < 10; ++k) {
        float4 v = *(const float4*)(p + 4 * k);
        r[4 * k + 0] = v.x; r[4 * k + 1] = v.y;
        r[4 * k + 2] = v.z; r[4 * k + 3] = v.w;
    }
    #pragma unroll
    for (int k = 0; k < 40; ++k) {
        const int c = col0 - 16 + k;
        if (c < 0 || c >= W) r[k] = 0.f;
    }

    // window for column col0: cols [col0-15, col0+15] -> k = 1..31
    float run = 0.f;
    #pragma unroll
    for (int k = 1; k <= 31; ++k) run += r[k];

    const float4 t0 = *(const float4*)(tgt + rowbase + col0);
    const float4 t1 = *(const float4*)(tgt + rowbase + col0 + 4);
    const float4 i0 = *(const float4*)(inp + rowbase + col0);
    const float4 i1 = *(const float4*)(inp + rowbase + col0 + 4);
    const float tv[8] = {t0.x, t0.y, t0.z, t0.w, t1.x, t1.y, t1.z, t1.w};
    const float iv[8] = {i0.x, i0.y, i0.z, i0.w, i1.x, i1.y, i1.z, i1.w};

    const float inv = 1.0f / (float)(KW * KW);
    float aI = 0.f, aA = 0.f, aB = 0.f;
    #pragma unroll
    for (int j = 0; j < 8; ++j) {
        const float wgt = 1.0f + 5.0f * fabsf(run * inv - tv[j]);
        aI += iv[j] * tv[j] * wgt;
        aA += iv[j] * wgt;
        aB += tv[j] * wgt;
        // advance window to column col0+j+1: add col0+j+16 (k=j+32), sub col0+j-15 (k=j+1)
        run += r[j + 32] - r[j + 1];
    }

    // wave reduction (64 lanes)
    #pragma unroll
    for (int off = 32; off > 0; off >>= 1) {
        aI += __shfl_down(aI, off, 64);
        aA += __shfl_down(aA, off, 64);
        aB += __shfl_down(aB, off, 64);
    }

    // block reduction across 4 waves, then 3 atomics per block (64B apart)
    __shared__ float part[3][4];
    if (lane == 0) {
        part[0][wave] = aI; part[1][wave] = aA; part[2][wave] = aB;
    }
    __syncthreads();
    if (threadIdx.x == 0) {
        atomicAdd(&acc[0],  part[0][0] + part[0][1] + part[0][2] + part[0][3]);
        atomicAdd(&acc[16], part[1][0] + part[1][1] + part[1][2] + part[1][3]);
        atomicAdd(&acc[32], part[2][0] + part[2][1] + part[2][2] + part[2][3]);
    }
}

// ---------------------------------------------------------------------------
// Pass 3: scalar finalize.
// ---------------------------------------------------------------------------
__global__ void finalize_kernel(const float* __restrict__ acc, float* __restrict__ out) {
    const float I  = acc[0];
    const float A  = acc[16];
    const float Bv = acc[32];
    out[0] = 1.0f - (2.0f * I + 1.0f) / (A + Bv + 1.0f);
}

extern "C" void kernel_launch(void* const* d_in, const int* in_sizes, int n_in,
                              void* d_out, int out_size, void* d_ws, size_t ws_size,
                              hipStream_t stream) {
    const float* inp = (const float*)d_in[0];   // "input"
    const float* tgt = (const float*)d_in[1];   // "target"
    float* out = (float*)d_out;

    // workspace layout:
    //   [0, 256)          : accumulators (floats at 0, 16, 32), zeroed each call;
    //                       also provides 64B slack before colsum for the
    //                       negative-offset edge reads in pass 2.
    //   [256, 256 + 64MB) : colsum (B*H*W floats); pass 2 may read 64B past the
    //                       end (masked to zero) -- ws_size slack covers it.
    float* acc    = (float*)d_ws;
    float* colsum = (float*)((char*)d_ws + 256);

    hipMemsetAsync(d_ws, 0, 256, stream);
    vbox_kernel<<<BATCH * NSEG * W / 256, 256, 0, stream>>>(tgt, colsum);
    hbox_reduce_kernel<<<BATCH * H / 4, 256, 0, stream>>>(colsum, tgt, inp, acc);
    finalize_kernel<<<1, 1, 0, stream>>>(acc, out);
}

// Round 2
// 182.063 us; speedup vs baseline: 2.0059x; 2.0059x over previous
//
#include <hip/hip_runtime.h>

// WeightedDiceLoss on MI355X.
// input, target: (64,1,512,512) fp32. Output: scalar fp32.
// weight = 1 + 5*|box31(target) - target|, box31 = separable 31x31 box filter,
// zero padding 15, always divide by 961 (count_include_pad=True).
// loss = 1 - (2*sum(i*t*w) + 1) / (sum(i*w) + sum(t*w) + 1)

#define BATCH 64
#define H     512
#define W     512
#define KW    31
#define PADR  15

// Pass 1 config: thread handles 4 consecutive columns (float4) over SEG rows.
#define NSEG  32           // vertical segments per column
#define SEG   (H / NSEG)   // 16

#define HBOX_BLOCKS (BATCH * H / 4)   // 8192, one wave per image row

// ---------------------------------------------------------------------------
// Pass 1: vertical box sum over target -> colsum[b,h,w] = sum_{j=h-15..h+15} t
// One thread per (b, seg, w/4); float4 running sliding-window sum down the
// column. 1024 blocks (4/CU) for latency hiding; wave reads 1KB/instr.
// ---------------------------------------------------------------------------
__global__ __launch_bounds__(256) void vbox_kernel(const float* __restrict__ tgt,
                                                   float* __restrict__ colsum) {
    const int t    = blockIdx.x * 256 + threadIdx.x;   // 0 .. BATCH*NSEG*128-1
    const int w4   = t & (W / 4 - 1);                  // column group (x4)
    const int rest = t >> 7;
    const int seg  = rest & (NSEG - 1);
    const int b    = rest >> 5;
    const size_t base = (size_t)b * H * W + (size_t)w4 * 4;
    const int h0 = seg * SEG;

    float rx = 0.f, ry = 0.f, rz = 0.f, rw = 0.f;
    #pragma unroll
    for (int j = -PADR; j <= PADR; ++j) {
        const int r = h0 + j;
        if (r >= 0 && r < H) {
            const float4 v = *(const float4*)(tgt + base + (size_t)r * W);
            rx += v.x; ry += v.y; rz += v.z; rw += v.w;
        }
    }

    #pragma unroll
    for (int h = h0; h < h0 + SEG; ++h) {
        float4 o; o.x = rx; o.y = ry; o.z = rz; o.w = rw;
        *(float4*)(colsum + base + (size_t)h * W) = o;
        const int add = h + PADR + 1;
        const int sub = h - PADR;
        if (add < H) {
            const float4 v = *(const float4*)(tgt + base + (size_t)add * W);
            rx += v.x; ry += v.y; rz += v.z; rw += v.w;
        }
        if (sub >= 0) {
            const float4 v = *(const float4*)(tgt + base + (size_t)sub * W);
            rx -= v.x; ry -= v.y; rz -= v.z; rw -= v.w;
        }
    }
}

// ---------------------------------------------------------------------------
// Pass 2: horizontal box sum (register sliding window) + fused weighted sums.
// One wave (64 lanes) per image row; lane handles 8 consecutive columns.
// No LDS for the window (no bank conflicts); NO atomics -- each block writes
// one float4 partial {I, A, B, 0} to workspace.
// ---------------------------------------------------------------------------
__global__ __launch_bounds__(256) void hbox_reduce_kernel(const float* __restrict__ colsum,
                                                          const float* __restrict__ tgt,
                                                          const float* __restrict__ inp,
                                                          float4* __restrict__ partials) {
    const int wave = threadIdx.x >> 6;
    const int lane = threadIdx.x & 63;
    const int row  = blockIdx.x * 4 + wave;            // 0 .. BATCH*H-1
    const size_t rowbase = (size_t)row * W;
    const int col0 = lane * 8;

    // r[k] holds colsum at column (col0 - 16 + k), k = 0..39.
    // Reads may run past array edges by <=64B (workspace slack); invalid
    // entries are zeroed below (zero padding semantics).
    float r[40];
    const float* p = colsum + rowbase + col0 - 16;
    #pragma unroll
    for (int k = 0; k < 10; ++k) {
        const float4 v = *(const float4*)(p + 4 * k);
        r[4 * k + 0] = v.x; r[4 * k + 1] = v.y;
        r[4 * k + 2] = v.z; r[4 * k + 3] = v.w;
    }
    #pragma unroll
    for (int k = 0; k < 40; ++k) {
        const int c = col0 - 16 + k;
        if (c < 0 || c >= W) r[k] = 0.f;
    }

    // window for column col0: cols [col0-15, col0+15] -> k = 1..31
    float run = 0.f;
    #pragma unroll
    for (int k = 1; k <= 31; ++k) run += r[k];

    const float4 t0 = *(const float4*)(tgt + rowbase + col0);
    const float4 t1 = *(const float4*)(tgt + rowbase + col0 + 4);
    const float4 i0 = *(const float4*)(inp + rowbase + col0);
    const float4 i1 = *(const float4*)(inp + rowbase + col0 + 4);
    const float tv[8] = {t0.x, t0.y, t0.z, t0.w, t1.x, t1.y, t1.z, t1.w};
    const float iv[8] = {i0.x, i0.y, i0.z, i0.w, i1.x, i1.y, i1.z, i1.w};

    const float inv = 1.0f / (float)(KW * KW);
    float aI = 0.f, aA = 0.f, aB = 0.f;
    #pragma unroll
    for (int j = 0; j < 8; ++j) {
        const float wgt = 1.0f + 5.0f * fabsf(run * inv - tv[j]);
        aI += iv[j] * tv[j] * wgt;
        aA += iv[j] * wgt;
        aB += tv[j] * wgt;
        // advance window: add col0+j+16 (k=j+32), sub col0+j-15 (k=j+1)
        run += r[j + 32] - r[j + 1];
    }

    // wave reduction (64 lanes)
    #pragma unroll
    for (int off = 32; off > 0; off >>= 1) {
        aI += __shfl_down(aI, off, 64);
        aA += __shfl_down(aA, off, 64);
        aB += __shfl_down(aB, off, 64);
    }

    // block reduction across 4 waves; ONE uncontended float4 store per block
    __shared__ float part[3][4];
    if (lane == 0) {
        part[0][wave] = aI; part[1][wave] = aA; part[2][wave] = aB;
    }
    __syncthreads();
    if (threadIdx.x == 0) {
        float4 o;
        o.x = part[0][0] + part[0][1] + part[0][2] + part[0][3];
        o.y = part[1][0] + part[1][1] + part[1][2] + part[1][3];
        o.z = part[2][0] + part[2][1] + part[2][2] + part[2][3];
        o.w = 0.f;
        partials[blockIdx.x] = o;
    }
}

// ---------------------------------------------------------------------------
// Pass 3: reduce 8192 partials + finalize. One block, 1024 threads (16 waves).
// ---------------------------------------------------------------------------
__global__ __launch_bounds__(1024) void reduce_kernel(const float4* __restrict__ partials,
                                                      float* __restrict__ out) {
    const int tid = threadIdx.x;
    float aI = 0.f, aA = 0.f, aB = 0.f;
    #pragma unroll
    for (int i = tid; i < HBOX_BLOCKS; i += 1024) {
        const float4 v = partials[i];
        aI += v.x; aA += v.y; aB += v.z;
    }
    #pragma unroll
    for (int off = 32; off > 0; off >>= 1) {
        aI += __shfl_down(aI, off, 64);
        aA += __shfl_down(aA, off, 64);
        aB += __shfl_down(aB, off, 64);
    }
    __shared__ float s[3][16];
    const int wv = tid >> 6, ln = tid & 63;
    if (ln == 0) { s[0][wv] = aI; s[1][wv] = aA; s[2][wv] = aB; }
    __syncthreads();
    if (tid == 0) {
        float I = 0.f, A = 0.f, Bv = 0.f;
        #pragma unroll
        for (int k = 0; k < 16; ++k) { I += s[0][k]; A += s[1][k]; Bv += s[2][k]; }
        out[0] = 1.0f - (2.0f * I + 1.0f) / (A + Bv + 1.0f);
    }
}

extern "C" void kernel_launch(void* const* d_in, const int* in_sizes, int n_in,
                              void* d_out, int out_size, void* d_ws, size_t ws_size,
                              hipStream_t stream) {
    const float* inp = (const float*)d_in[0];   // "input"
    const float* tgt = (const float*)d_in[1];   // "target"
    float* out = (float*)d_out;

    // workspace layout:
    //   [0, 256)                      : slack for pass-2 negative-offset edge reads
    //   [256, 256+128KB)              : per-block partials (8192 x float4)
    //   [131328, 131328+64MB)         : colsum; pass 2 may read 96B past the end
    //                                   (masked to zero) -- ws slack covers it.
    float4* partials = (float4*)((char*)d_ws + 256);
    float*  colsum   = (float*)((char*)d_ws + 256 + (size_t)HBOX_BLOCKS * 16);

    vbox_kernel<<<BATCH * NSEG * (W / 4) / 256, 256, 0, stream>>>(tgt, colsum);
    hbox_reduce_kernel<<<HBOX_BLOCKS, 256, 0, stream>>>(colsum, tgt, inp, partials);
    reduce_kernel<<<1, 1024, 0, stream>>>(partials, out);
}

// Round 3
// 169.016 us; speedup vs baseline: 2.1607x; 1.0772x over previous
//
#include <hip/hip_runtime.h>

// WeightedDiceLoss on MI355X -- FUSED single-pass version.
// input, target: (64,1,512,512) fp32. Output: scalar fp32.
// weight = 1 + 5*|box31(target) - target|; loss = 1 - (2*I+1)/(A+B+1).
//
// One wave (64 lanes) owns a 16-row band of one image, full 512-col width.
// Lane maintains 8 vertical running sums (its 8 contiguous columns); the
// 40-wide horizontal window is built per row via cross-lane shuffles (no LDS,
// no colsum round-trip). Mandatory HBM traffic: 128 MB (target + input once;
// band-halo re-reads served by L3).

#define BATCH 64
#define H     512
#define W     512
#define PADR  15
#define NSEG  32                 // row-bands per image
#define RB    (H / NSEG)         // 16 rows per band
#define NBLK  (BATCH * NSEG)     // 2048 blocks (1 wave each)

__global__ __launch_bounds__(64) void fused_kernel(const float* __restrict__ tgt,
                                                   const float* __restrict__ inp,
                                                   float4* __restrict__ partials) {
    const int lane = threadIdx.x;            // 0..63
    const int blk  = blockIdx.x;             // 0..NBLK-1
    const int band = blk & (NSEG - 1);
    const int b    = blk >> 5;               // image index
    const int r0   = band * RB;
    const int col0 = lane * 8;
    const float* timg = tgt + (size_t)b * H * W;
    const float* iimg = inp + (size_t)b * H * W;

    // --- vertical running sums vr[k] = sum_{r in [h-15,h+15]} tgt[r][col0+k]
    float vr[8];
    #pragma unroll
    for (int k = 0; k < 8; ++k) vr[k] = 0.f;
    #pragma unroll
    for (int j = -PADR; j <= PADR; ++j) {
        const int r = r0 + j;
        if (r >= 0 && r < H) {
            const float4 a = *(const float4*)(timg + (size_t)r * W + col0);
            const float4 c = *(const float4*)(timg + (size_t)r * W + col0 + 4);
            vr[0] += a.x; vr[1] += a.y; vr[2] += a.z; vr[3] += a.w;
            vr[4] += c.x; vr[5] += c.y; vr[6] += c.z; vr[7] += c.w;
        }
    }

    // per-lane column-validity mask for the 40-wide window (zero padding)
    float validf[40];
    #pragma unroll
    for (int m = 0; m < 40; ++m) {
        const int c = col0 - 16 + m;
        validf[m] = (c >= 0 && c < W) ? 1.f : 0.f;
    }

    const float inv = 1.0f / 961.0f;
    float aI = 0.f, aA = 0.f, aB = 0.f;

    for (int h = r0; h < r0 + RB; ++h) {
        // --- build 40-col window of colsum(row h) via shuffles
        // wd[m] = colsum at column (col0 - 16 + m)
        float wd[40];
        #pragma unroll
        for (int k = 0; k < 8; ++k) {
            wd[k]      = __shfl_up(vr[k], 2, 64);
            wd[k + 8]  = __shfl_up(vr[k], 1, 64);
            wd[k + 16] = vr[k];
            wd[k + 24] = __shfl_down(vr[k], 1, 64);
            wd[k + 32] = __shfl_down(vr[k], 2, 64);
        }
        #pragma unroll
        for (int m = 0; m < 40; ++m) wd[m] *= validf[m];

        // window for col0: wd[1..31]
        float run = 0.f;
        #pragma unroll
        for (int m = 1; m <= 31; ++m) run += wd[m];

        const float4 t0 = *(const float4*)(timg + (size_t)h * W + col0);
        const float4 t1 = *(const float4*)(timg + (size_t)h * W + col0 + 4);
        const float4 i0 = *(const float4*)(iimg + (size_t)h * W + col0);
        const float4 i1 = *(const float4*)(iimg + (size_t)h * W + col0 + 4);
        const float tv[8] = {t0.x, t0.y, t0.z, t0.w, t1.x, t1.y, t1.z, t1.w};
        const float iv[8] = {i0.x, i0.y, i0.z, i0.w, i1.x, i1.y, i1.z, i1.w};

        #pragma unroll
        for (int j = 0; j < 8; ++j) {
            const float wgt = 1.0f + 5.0f * fabsf(run * inv - tv[j]);
            aI += iv[j] * tv[j] * wgt;
            aA += iv[j] * wgt;
            aB += tv[j] * wgt;
            run += wd[j + 32] - wd[j + 1];   // slide window one column right
        }

        // --- advance vertical window to row h+1: add h+16, sub h-15
        const int add = h + PADR + 1;
        const int sub = h - PADR;
        if (add < H) {
            const float4 a = *(const float4*)(timg + (size_t)add * W + col0);
            const float4 c = *(const float4*)(timg + (size_t)add * W + col0 + 4);
            vr[0] += a.x; vr[1] += a.y; vr[2] += a.z; vr[3] += a.w;
            vr[4] += c.x; vr[5] += c.y; vr[6] += c.z; vr[7] += c.w;
        }
        if (sub >= 0) {
            const float4 a = *(const float4*)(timg + (size_t)sub * W + col0);
            const float4 c = *(const float4*)(timg + (size_t)sub * W + col0 + 4);
            vr[0] -= a.x; vr[1] -= a.y; vr[2] -= a.z; vr[3] -= a.w;
            vr[4] -= c.x; vr[5] -= c.y; vr[6] -= c.z; vr[7] -= c.w;
        }
    }

    // wave reduction (64 lanes), one uncontended float4 store per block
    #pragma unroll
    for (int off = 32; off > 0; off >>= 1) {
        aI += __shfl_down(aI, off, 64);
        aA += __shfl_down(aA, off, 64);
        aB += __shfl_down(aB, off, 64);
    }
    if (lane == 0) {
        float4 o; o.x = aI; o.y = aA; o.z = aB; o.w = 0.f;
        partials[blk] = o;
    }
}

// ---------------------------------------------------------------------------
// Reduce 2048 partials + finalize. One block, 1024 threads (16 waves).
// ---------------------------------------------------------------------------
__global__ __launch_bounds__(1024) void reduce_kernel(const float4* __restrict__ partials,
                                                      float* __restrict__ out) {
    const int tid = threadIdx.x;
    float aI = 0.f, aA = 0.f, aB = 0.f;
    #pragma unroll
    for (int i = tid; i < NBLK; i += 1024) {
        const float4 v = partials[i];
        aI += v.x; aA += v.y; aB += v.z;
    }
    #pragma unroll
    for (int off = 32; off > 0; off >>= 1) {
        aI += __shfl_down(aI, off, 64);
        aA += __shfl_down(aA, off, 64);
        aB += __shfl_down(aB, off, 64);
    }
    __shared__ float s[3][16];
    const int wv = tid >> 6, ln = tid & 63;
    if (ln == 0) { s[0][wv] = aI; s[1][wv] = aA; s[2][wv] = aB; }
    __syncthreads();
    if (tid == 0) {
        float I = 0.f, A = 0.f, Bv = 0.f;
        #pragma unroll
        for (int k = 0; k < 16; ++k) { I += s[0][k]; A += s[1][k]; Bv += s[2][k]; }
        out[0] = 1.0f - (2.0f * I + 1.0f) / (A + Bv + 1.0f);
    }
}

extern "C" void kernel_launch(void* const* d_in, const int* in_sizes, int n_in,
                              void* d_out, int out_size, void* d_ws, size_t ws_size,
                              hipStream_t stream) {
    const float* inp = (const float*)d_in[0];   // "input"
    const float* tgt = (const float*)d_in[1];   // "target"
    float* out = (float*)d_out;

    // workspace: [0, NBLK*16) per-block partials (float4). Written before read;
    // no zero-init needed.
    float4* partials = (float4*)d_ws;

    fused_kernel<<<NBLK, 64, 0, stream>>>(tgt, inp, partials);
    reduce_kernel<<<1, 1024, 0, stream>>>(partials, out);
}